// Round 2
// baseline (220.545 us; speedup 1.0000x reference)
//
#include <hip/hip_runtime.h>
#include <hip/hip_bf16.h>
#include <math.h>

#define NS 4096          // samples per view
#define NI 8192          // total instances (2 views)
#define DIM 512
#define TEMP_INV 2.0f    // 1/t, t = 0.5
#define TILE 256         // output tile side
#define NBLK 32          // NI/TILE tile blocks per side
#define NTRI (NBLK * (NBLK + 1) / 2)   // 528 upper-triangle tiles
#define BK 64            // k-elems staged per step

typedef short v8s __attribute__((ext_vector_type(8)));   // 8 bf16 (4 VGPRs)
typedef float v4f __attribute__((ext_vector_type(4)));   // 4 fp32 acc

// async global->LDS, 16B per lane. LDS dest is wave-uniform base + lane*16.
__device__ __forceinline__ void gld16(const void* g, void* l) {
    __builtin_amdgcn_global_load_lds(
        (const __attribute__((address_space(1))) void*)g,
        (__attribute__((address_space(3))) void*)l, 16, 0, 0);
}

// ---------------------------------------------------------------------------
// Kernel 1: norms + positive dots (fp32), cast X -> bf16; also zeros rowsum.
// ---------------------------------------------------------------------------
__global__ __launch_bounds__(256) void prep_kernel(
        const float* __restrict__ x1, const float* __restrict__ x2,
        __hip_bfloat16* __restrict__ Xb, float* __restrict__ rnorm,
        float* __restrict__ posdot, float* __restrict__ rowsum) {
    const int t = threadIdx.x;
    if (t < 4) rowsum[blockIdx.x * 4 + t] = 0.f;   // 2048 blocks x 4 = NI
    const int sub = t >> 7;
    const int c4 = t & 127;
    const int i = blockIdx.x * 2 + sub;
    const float4 a = ((const float4*)(x1 + (size_t)i * DIM))[c4];
    const float4 b = ((const float4*)(x2 + (size_t)i * DIM))[c4];
    float s1 = a.x*a.x + a.y*a.y + a.z*a.z + a.w*a.w;
    float s2 = b.x*b.x + b.y*b.y + b.z*b.z + b.w*b.w;
    float dd = a.x*b.x + a.y*b.y + a.z*b.z + a.w*b.w;

    auto bfbits = [](float v) -> unsigned short {
        __hip_bfloat16 h = __float2bfloat16(v);
        return *(unsigned short*)&h;
    };
    ushort4 pa = { bfbits(a.x), bfbits(a.y), bfbits(a.z), bfbits(a.w) };
    ushort4 pb = { bfbits(b.x), bfbits(b.y), bfbits(b.z), bfbits(b.w) };
    ((ushort4*)(Xb + (size_t)i * DIM))[c4] = pa;
    ((ushort4*)(Xb + (size_t)(i + NS) * DIM))[c4] = pb;

    #pragma unroll
    for (int off = 32; off; off >>= 1) {
        s1 += __shfl_down(s1, off, 64);
        s2 += __shfl_down(s2, off, 64);
        dd += __shfl_down(dd, off, 64);
    }
    __shared__ float red[2][2][3];
    if ((t & 63) == 0) {
        const int w = (t >> 6) & 1;
        red[sub][w][0] = s1; red[sub][w][1] = s2; red[sub][w][2] = dd;
    }
    __syncthreads();
    if ((t & 127) == 0) {
        s1 = red[sub][0][0] + red[sub][1][0];
        s2 = red[sub][0][1] + red[sub][1][1];
        dd = red[sub][0][2] + red[sub][1][2];
        rnorm[i]      = 1.0f / sqrtf(s1);
        rnorm[i + NS] = 1.0f / sqrtf(s2);
        posdot[i] = dd;
    }
}

// ---------------------------------------------------------------------------
// Kernel 2: upper-triangle 256x256 tiles of G = Xb*Xb^T.
// 4 waves, each owns a 128x128 quadrant (8x8 16x16x32 frags, 256 acc VGPRs).
// Per block-stage: 512 MFMA (2483 CU-cyc) vs ~2250 cyc LDS traffic -> the
// matrix pipe is the saturated resource (round-0's 128^2 tile left it at 23%
// with ~50% pure per-stage overhead; round-1 BK=32 doubled that overhead).
// BK=64 double-buffered (128 KB -> 1 block/CU); prefetch issued BEFORE
// compute so the vmcnt drain at the next barrier hides under ~2800 cyc of
// MFMAs. LDS row stride 128B = 8 x 16B chunks, slot cs = kc ^ (row&7)
// (round-0's layout, measured 0 bank conflicts).
// ---------------------------------------------------------------------------
__global__ __launch_bounds__(256, 1) void sim_kernel(
        const __hip_bfloat16* __restrict__ Xbh, const float* __restrict__ rnorm,
        float* __restrict__ rowsum, float* __restrict__ negpart) {
    // --- triangular decode: id -> (bi, bj), bi<=bj, NBLK=32
    const int id = blockIdx.x;
    int bi = (int)((65.0f - sqrtf(4225.0f - 8.0f * (float)id)) * 0.5f);
    int base = bi * (65 - bi) / 2;
    if (id < base)                       { --bi; base = bi * (65 - bi) / 2; }
    else if (id >= base + (NBLK - bi))   { ++bi; base = bi * (65 - bi) / 2; }
    const int bj = bi + (id - base);
    const bool offdiag = (bj != bi);
    const int i0 = bi * TILE, j0 = bj * TILE;

    __shared__ __align__(16) short lds[2][2][TILE * BK];   // [buf][A/B], 128 KB
    __shared__ float sRow[2][TILE];            // [wc][row]
    __shared__ float sCol[2][TILE];            // [wr][col]
    __shared__ float sNeg[4];

    const int t = threadIdx.x;
    const int lane = t & 63, wv = t >> 6;
    const int wr = wv >> 1, wc = wv & 1;       // 2x2 waves, each 128x128
    const int r16 = lane & 15, quad = lane >> 4;

    const short* X = reinterpret_cast<const short*>(Xbh);

    // --- staging: per wave 8 A-instrs + 8 B-instrs per stage (64 KB/block).
    // instr q covers 64 chunks; lane L -> lin=(wv*8+q)*64+L, row=lin>>3,
    // slot cs=lin&7 holds global k-chunk kc = cs^(row&7).
    int gA[8], gB[8], lOff[8];
    #pragma unroll
    for (int q = 0; q < 8; ++q) {
        const int lin = (wv * 8 + q) * 64 + lane;
        const int row = lin >> 3, cs = lin & 7;
        const int kc = cs ^ (row & 7);
        gA[q] = (i0 + row) * DIM + kc * 8;     // short index
        gB[q] = (j0 + row) * DIM + kc * 8;
        lOff[q] = (wv * 8 + q) * 512;          // shorts; HW adds lane*16B
    }

    // --- fragment LDS byte offsets (swizzled, s2=0; s2=1 is ^64)
    int offA[8], offB[8];
    #pragma unroll
    for (int tt = 0; tt < 8; ++tt) {
        const int tra = wr * 128 + tt * 16 + r16;
        offA[tt] = tra * 128 + ((quad ^ (tra & 7)) * 16);
        const int trb = wc * 128 + tt * 16 + r16;
        offB[tt] = trb * 128 + ((quad ^ (trb & 7)) * 16);
    }

    v4f acc[8][8];
    #pragma unroll
    for (int a = 0; a < 8; ++a)
        #pragma unroll
        for (int b = 0; b < 8; ++b)
            acc[a][b] = (v4f){0.f, 0.f, 0.f, 0.f};

    // --- prologue: stage first chunk into buf0
    #pragma unroll
    for (int q = 0; q < 8; ++q) {
        gld16(X + gA[q], &lds[0][0][lOff[q]]);
        gld16(X + gB[q], &lds[0][1][lOff[q]]);
    }

    // --- main loop: 8 stages of BK=64
    for (int s = 0; s < DIM / BK; ++s) {
        const int cur = s & 1;
        __syncthreads();                       // buf[cur] complete (vmcnt drain)
        if (s + 1 < DIM / BK) {                // prefetch next (in flight during compute)
            const int k0 = (s + 1) * BK;
            #pragma unroll
            for (int q = 0; q < 8; ++q) {
                gld16(X + gA[q] + k0, &lds[1 - cur][0][lOff[q]]);
                gld16(X + gB[q] + k0, &lds[1 - cur][1][lOff[q]]);
            }
        }
        const char* bufA = (const char*)&lds[cur][0][0];
        const char* bufB = (const char*)&lds[cur][1][0];
        #pragma unroll
        for (int s2 = 0; s2 < 2; ++s2) {
            v8s af[8], bf[8];
            #pragma unroll
            for (int tt = 0; tt < 8; ++tt) {
                af[tt] = *(const v8s*)(bufA + (offA[tt] ^ (s2 * 64)));
                bf[tt] = *(const v8s*)(bufB + (offB[tt] ^ (s2 * 64)));
            }
            #pragma unroll
            for (int ta = 0; ta < 8; ++ta)
                #pragma unroll
                for (int tb = 0; tb < 8; ++tb)
                    acc[ta][tb] = __builtin_amdgcn_mfma_f32_16x16x32_bf16(
                        af[ta], bf[tb], acc[ta][tb], 0, 0, 0);
        }
    }

    // --- epilogue: sim2 = 2*D*r_i*r_j; masked (j==i, j==i^NS) -> exp contributes 1
    float rc[8];
    int colg[8];
    #pragma unroll
    for (int tb = 0; tb < 8; ++tb) {
        colg[tb] = j0 + wc * 128 + tb * 16 + r16;
        rc[tb] = rnorm[colg[tb]];
    }
    float negacc = 0.f;
    float colacc[8] = {0.f, 0.f, 0.f, 0.f, 0.f, 0.f, 0.f, 0.f};
    #pragma unroll
    for (int ta = 0; ta < 8; ++ta) {
        #pragma unroll
        for (int r = 0; r < 4; ++r) {
            const int rowl = wr * 128 + ta * 16 + quad * 4 + r;
            const int rowg = i0 + rowl;
            const float rr = rnorm[rowg] * TEMP_INV;
            float rowe = 0.f;
            #pragma unroll
            for (int tb = 0; tb < 8; ++tb) {
                const float sim2 = acc[ta][tb][r] * rr * rc[tb];
                const bool masked = (colg[tb] == rowg) || (colg[tb] == (rowg ^ NS));
                const float e = masked ? 1.0f : __expf(sim2);
                rowe   += e;
                negacc += masked ? 0.0f : sim2;
                colacc[tb] += e;
            }
            #pragma unroll
            for (int off = 1; off < 16; off <<= 1)
                rowe += __shfl_xor(rowe, off, 64);
            if (r16 == 0) sRow[wc][rowl] = rowe;
        }
    }
    #pragma unroll
    for (int tb = 0; tb < 8; ++tb) {
        colacc[tb] += __shfl_xor(colacc[tb], 16, 64);
        colacc[tb] += __shfl_xor(colacc[tb], 32, 64);
        if (quad == 0) sCol[wr][wc * 128 + tb * 16 + r16] = colacc[tb];
    }
    if (offdiag) negacc *= 2.0f;
    #pragma unroll
    for (int off = 1; off < 64; off <<= 1)
        negacc += __shfl_xor(negacc, off, 64);
    if (lane == 0) sNeg[wv] = negacc;

    __syncthreads();

    if (t < TILE) {
        atomicAdd(&rowsum[i0 + t], sRow[0][t] + sRow[1][t]);
        if (offdiag)
            atomicAdd(&rowsum[j0 + t], sCol[0][t] + sCol[1][t]);
    }
    if (t == 0)
        negpart[id] = sNeg[0] + sNeg[1] + sNeg[2] + sNeg[3];
}

// ---------------------------------------------------------------------------
// Kernel 3: final scalars. E_i = rowsum[i] (includes +2 from masked entries).
// ---------------------------------------------------------------------------
__global__ __launch_bounds__(1024) void final_kernel(
        const float* __restrict__ rowsum, const float* __restrict__ rnorm,
        const float* __restrict__ posdot, const float* __restrict__ negpart,
        float* __restrict__ out) {
    const int t = threadIdx.x;
    float lsum = 0.f, psum = 0.f, nsum = 0.f;
    #pragma unroll
    for (int i = t; i < NI; i += 1024) {
        const int s = i & (NS - 1);
        const float sp = posdot[s] * rnorm[i] * rnorm[i ^ NS] * TEMP_INV;
        const float E = rowsum[i];
        lsum += logf(expf(sp) + E) - sp;
        psum += sp;
    }
    if (t < NTRI)
        nsum = negpart[t];
    __shared__ float red[3][16];
    #pragma unroll
    for (int off = 32; off; off >>= 1) {
        lsum += __shfl_down(lsum, off, 64);
        psum += __shfl_down(psum, off, 64);
        nsum += __shfl_down(nsum, off, 64);
    }
    if ((t & 63) == 0) {
        red[0][t >> 6] = lsum; red[1][t >> 6] = psum; red[2][t >> 6] = nsum;
    }
    __syncthreads();
    if (t == 0) {
        lsum = 0.f; psum = 0.f; nsum = 0.f;
        #pragma unroll
        for (int w = 0; w < 16; ++w) {
            lsum += red[0][w]; psum += red[1][w]; nsum += red[2][w];
        }
        out[0] = lsum / (float)NI;
        out[1] = psum / (float)NI;
        out[2] = nsum / ((float)NI * (float)(NI - 2));
    }
}

// ---------------------------------------------------------------------------
extern "C" void kernel_launch(void* const* d_in, const int* in_sizes, int n_in,
                              void* d_out, int out_size, void* d_ws, size_t ws_size,
                              hipStream_t stream) {
    const float* x1 = (const float*)d_in[0];
    const float* x2 = (const float*)d_in[1];
    float* out = (float*)d_out;

    char* ws = (char*)d_ws;
    __hip_bfloat16* Xb = (__hip_bfloat16*)ws;                 // NI*DIM*2 = 8 MB
    float* rnorm  = (float*)(ws + (size_t)NI * DIM * 2);      // NI
    float* posdot = rnorm + NI;                               // NS
    float* rowsum = posdot + NS;                              // NI (zeroed in prep)
    float* negpart = rowsum + NI;                             // NTRI (all written)

    prep_kernel<<<NS / 2, 256, 0, stream>>>(x1, x2, Xb, rnorm, posdot, rowsum);

    sim_kernel<<<NTRI, 256, 0, stream>>>(Xb, rnorm, rowsum, negpart);

    final_kernel<<<1, 1024, 0, stream>>>(rowsum, rnorm, posdot, negpart, out);
}

// Round 3
// 149.960 us; speedup vs baseline: 1.4707x; 1.4707x over previous
//
#include <hip/hip_runtime.h>
#include <hip/hip_bf16.h>
#include <math.h>

#define NS 4096          // samples per view
#define NI 8192          // total instances (2 views)
#define DIM 512
#define TEMP_INV 2.0f    // 1/t, t = 0.5
#define TILE 256         // output tile side
#define NBLK 32          // NI/TILE tile blocks per side
#define NTRI (NBLK * (NBLK + 1) / 2)   // 528 upper-triangle tiles
#define BK 64            // k-elems staged per step
#define NSTG (DIM / BK)  // 8 stages

typedef short v8s __attribute__((ext_vector_type(8)));   // 8 bf16 (4 VGPRs)
typedef float v4f __attribute__((ext_vector_type(4)));   // 4 fp32 acc

// async global->LDS, 16B per lane. LDS dest is wave-uniform base + lane*16.
__device__ __forceinline__ void gld16(const void* g, void* l) {
    __builtin_amdgcn_global_load_lds(
        (const __attribute__((address_space(1))) void*)g,
        (__attribute__((address_space(3))) void*)l, 16, 0, 0);
}

// ---------------------------------------------------------------------------
// Kernel 1: norms + positive dots (fp32), cast X -> bf16; also zeros rowsum.
// ---------------------------------------------------------------------------
__global__ __launch_bounds__(256) void prep_kernel(
        const float* __restrict__ x1, const float* __restrict__ x2,
        __hip_bfloat16* __restrict__ Xb, float* __restrict__ rnorm,
        float* __restrict__ posdot, float* __restrict__ rowsum) {
    const int t = threadIdx.x;
    if (t < 4) rowsum[blockIdx.x * 4 + t] = 0.f;   // 2048 blocks x 4 = NI
    const int sub = t >> 7;
    const int c4 = t & 127;
    const int i = blockIdx.x * 2 + sub;
    const float4 a = ((const float4*)(x1 + (size_t)i * DIM))[c4];
    const float4 b = ((const float4*)(x2 + (size_t)i * DIM))[c4];
    float s1 = a.x*a.x + a.y*a.y + a.z*a.z + a.w*a.w;
    float s2 = b.x*b.x + b.y*b.y + b.z*b.z + b.w*b.w;
    float dd = a.x*b.x + a.y*b.y + a.z*b.z + a.w*b.w;

    auto bfbits = [](float v) -> unsigned short {
        __hip_bfloat16 h = __float2bfloat16(v);
        return *(unsigned short*)&h;
    };
    ushort4 pa = { bfbits(a.x), bfbits(a.y), bfbits(a.z), bfbits(a.w) };
    ushort4 pb = { bfbits(b.x), bfbits(b.y), bfbits(b.z), bfbits(b.w) };
    ((ushort4*)(Xb + (size_t)i * DIM))[c4] = pa;
    ((ushort4*)(Xb + (size_t)(i + NS) * DIM))[c4] = pb;

    #pragma unroll
    for (int off = 32; off; off >>= 1) {
        s1 += __shfl_down(s1, off, 64);
        s2 += __shfl_down(s2, off, 64);
        dd += __shfl_down(dd, off, 64);
    }
    __shared__ float red[2][2][3];
    if ((t & 63) == 0) {
        const int w = (t >> 6) & 1;
        red[sub][w][0] = s1; red[sub][w][1] = s2; red[sub][w][2] = dd;
    }
    __syncthreads();
    if ((t & 127) == 0) {
        s1 = red[sub][0][0] + red[sub][1][0];
        s2 = red[sub][0][1] + red[sub][1][1];
        dd = red[sub][0][2] + red[sub][1][2];
        rnorm[i]      = 1.0f / sqrtf(s1);
        rnorm[i + NS] = 1.0f / sqrtf(s2);
        posdot[i] = dd;
    }
}

// ---------------------------------------------------------------------------
// Kernel 2: upper-triangle 256x256 tiles of G = Xb*Xb^T.
// 512 threads / 8 waves in a 2x4 grid; wave tile 128x64 -> acc[8][4] = 128
// VGPRs (rounds 1-2 spilled at 64/256 acc regs: WRITE_SIZE 60 MB scratch;
// this config peaks ~225 VGPR, under the 256 cliff).
// BK=64 double-buffered (128 KB -> 1 block/CU). Round-0 proven sync: barrier
// (drains prev prefetch, which had the whole ~2000-cyc compute to land) ->
// issue prefetch into other buffer -> compute. LDS row stride 128B = 8x16B
// chunks, slot cs = kc ^ (row&7): 0 bank conflicts measured (round 0).
// Per-tile floors: MFMA 16.5k CU-cyc, LDS ~17-21k cyc (different pipes).
// ---------------------------------------------------------------------------
__global__ __launch_bounds__(512, 1) void sim_kernel(
        const __hip_bfloat16* __restrict__ Xbh, const float* __restrict__ rnorm,
        float* __restrict__ rowsum, float* __restrict__ negpart) {
    // --- XCD-aware bijective swizzle: 528 = 8 * 66 exactly
    const int raw = blockIdx.x;
    const int id = (raw & 7) * 66 + (raw >> 3);
    // --- triangular decode: id -> (bi, bj), bi<=bj, NBLK=32
    int bi = (int)((65.0f - sqrtf(4225.0f - 8.0f * (float)id)) * 0.5f);
    int base = bi * (65 - bi) / 2;
    if (id < base)                       { --bi; base = bi * (65 - bi) / 2; }
    else if (id >= base + (NBLK - bi))   { ++bi; base = bi * (65 - bi) / 2; }
    const int bj = bi + (id - base);
    const bool offdiag = (bj != bi);
    const int i0 = bi * TILE, j0 = bj * TILE;

    __shared__ __align__(16) short lds[2][2][TILE * BK];   // [buf][A/B], 128 KB
    __shared__ float sRow[4][TILE];            // [wc][row]   4 KB
    __shared__ float sCol[2][TILE];            // [wr][col]   2 KB
    __shared__ float sNeg[8];

    const int t = threadIdx.x;                 // 0..511
    const int lane = t & 63, wv = t >> 6;      // 8 waves
    const int wr = wv >> 2, wc = wv & 3;       // 2 x 4 wave grid
    const int r16 = lane & 15, quad = lane >> 4;

    const short* X = reinterpret_cast<const short*>(Xbh);

    // --- staging: 64 KB/stage = 8 gld16 instrs block-wide (4 A + 4 B).
    // instr q covers chunks lin = q*512 + tid; row = lin>>3, slot cs = lin&7
    // holds global k-chunk kc = cs ^ (row&7). LDS dest base is wave-uniform.
    int gA[4], gB[4], lOff[4];
    #pragma unroll
    for (int q = 0; q < 4; ++q) {
        const int lin = q * 512 + t;
        const int row = lin >> 3, cs = lin & 7;
        const int kc = cs ^ (row & 7);
        gA[q] = (i0 + row) * DIM + kc * 8;     // short index
        gB[q] = (j0 + row) * DIM + kc * 8;
        lOff[q] = q * 4096 + wv * 512;         // shorts; HW adds lane*16B
    }

    // --- fragment LDS byte offsets (swizzled); s2=1 substep is ^64
    int offA[8], offB[4];
    #pragma unroll
    for (int tt = 0; tt < 8; ++tt) {
        const int tra = wr * 128 + tt * 16 + r16;
        offA[tt] = tra * 128 + ((quad ^ (tra & 7)) * 16);
    }
    #pragma unroll
    for (int tt = 0; tt < 4; ++tt) {
        const int trb = wc * 64 + tt * 16 + r16;
        offB[tt] = trb * 128 + ((quad ^ (trb & 7)) * 16);
    }

    v4f acc[8][4];
    #pragma unroll
    for (int a = 0; a < 8; ++a)
        #pragma unroll
        for (int b = 0; b < 4; ++b)
            acc[a][b] = (v4f){0.f, 0.f, 0.f, 0.f};

    // --- prologue: stage first chunk into buf0
    #pragma unroll
    for (int q = 0; q < 4; ++q) {
        gld16(X + gA[q], &lds[0][0][lOff[q]]);
        gld16(X + gB[q], &lds[0][1][lOff[q]]);
    }

    // --- main loop: 8 stages of BK=64
    for (int s = 0; s < NSTG; ++s) {
        const int cur = s & 1;
        __syncthreads();                       // buf[cur] complete (vmcnt drain)
        if (s + 1 < NSTG) {                    // prefetch next, in flight during compute
            const int k0 = (s + 1) * BK;
            #pragma unroll
            for (int q = 0; q < 4; ++q) {
                gld16(X + gA[q] + k0, &lds[1 - cur][0][lOff[q]]);
                gld16(X + gB[q] + k0, &lds[1 - cur][1][lOff[q]]);
            }
        }
        const char* bufA = (const char*)&lds[cur][0][0];
        const char* bufB = (const char*)&lds[cur][1][0];
        #pragma unroll
        for (int s2 = 0; s2 < 2; ++s2) {
            v8s af[8], bf[4];
            #pragma unroll
            for (int tt = 0; tt < 8; ++tt)
                af[tt] = *(const v8s*)(bufA + (offA[tt] ^ (s2 * 64)));
            #pragma unroll
            for (int tt = 0; tt < 4; ++tt)
                bf[tt] = *(const v8s*)(bufB + (offB[tt] ^ (s2 * 64)));
            __builtin_amdgcn_s_setprio(1);
            #pragma unroll
            for (int ta = 0; ta < 8; ++ta)
                #pragma unroll
                for (int tb = 0; tb < 4; ++tb)
                    acc[ta][tb] = __builtin_amdgcn_mfma_f32_16x16x32_bf16(
                        af[ta], bf[tb], acc[ta][tb], 0, 0, 0);
            __builtin_amdgcn_s_setprio(0);
        }
    }

    // --- epilogue: sim2 = 2*D*r_i*r_j; masked (j==i, j==i^NS) -> exp contributes 1
    float rc[4];
    int colg[4];
    #pragma unroll
    for (int tb = 0; tb < 4; ++tb) {
        colg[tb] = j0 + wc * 64 + tb * 16 + r16;
        rc[tb] = rnorm[colg[tb]];
    }
    float negacc = 0.f;
    float colacc[4] = {0.f, 0.f, 0.f, 0.f};
    #pragma unroll
    for (int ta = 0; ta < 8; ++ta) {
        #pragma unroll
        for (int r = 0; r < 4; ++r) {
            const int rowl = wr * 128 + ta * 16 + quad * 4 + r;
            const int rowg = i0 + rowl;
            const float rr = rnorm[rowg] * TEMP_INV;
            float rowe = 0.f;
            #pragma unroll
            for (int tb = 0; tb < 4; ++tb) {
                const float sim2 = acc[ta][tb][r] * rr * rc[tb];
                const bool masked = (colg[tb] == rowg) || (colg[tb] == (rowg ^ NS));
                const float e = masked ? 1.0f : __expf(sim2);
                rowe   += e;
                negacc += masked ? 0.0f : sim2;
                colacc[tb] += e;
            }
            #pragma unroll
            for (int off = 1; off < 16; off <<= 1)
                rowe += __shfl_xor(rowe, off, 64);
            if (r16 == 0) sRow[wc][rowl] = rowe;
        }
    }
    #pragma unroll
    for (int tb = 0; tb < 4; ++tb) {
        colacc[tb] += __shfl_xor(colacc[tb], 16, 64);
        colacc[tb] += __shfl_xor(colacc[tb], 32, 64);
        if (quad == 0) sCol[wr][wc * 64 + tb * 16 + r16] = colacc[tb];
    }
    if (offdiag) negacc *= 2.0f;
    #pragma unroll
    for (int off = 1; off < 64; off <<= 1)
        negacc += __shfl_xor(negacc, off, 64);
    if (lane == 0) sNeg[wv] = negacc;

    __syncthreads();

    if (t < TILE) {
        atomicAdd(&rowsum[i0 + t],
                  sRow[0][t] + sRow[1][t] + sRow[2][t] + sRow[3][t]);
    } else if (offdiag) {
        const int c = t - TILE;
        atomicAdd(&rowsum[j0 + c], sCol[0][c] + sCol[1][c]);
    }
    if (t == 0) {
        float n = 0.f;
        #pragma unroll
        for (int w = 0; w < 8; ++w) n += sNeg[w];
        negpart[id] = n;
    }
}

// ---------------------------------------------------------------------------
// Kernel 3: final scalars. E_i = rowsum[i] (includes +2 from masked entries).
// ---------------------------------------------------------------------------
__global__ __launch_bounds__(1024) void final_kernel(
        const float* __restrict__ rowsum, const float* __restrict__ rnorm,
        const float* __restrict__ posdot, const float* __restrict__ negpart,
        float* __restrict__ out) {
    const int t = threadIdx.x;
    float lsum = 0.f, psum = 0.f, nsum = 0.f;
    #pragma unroll
    for (int i = t; i < NI; i += 1024) {
        const int s = i & (NS - 1);
        const float sp = posdot[s] * rnorm[i] * rnorm[i ^ NS] * TEMP_INV;
        const float E = rowsum[i];
        lsum += logf(expf(sp) + E) - sp;
        psum += sp;
    }
    if (t < NTRI)
        nsum = negpart[t];
    __shared__ float red[3][16];
    #pragma unroll
    for (int off = 32; off; off >>= 1) {
        lsum += __shfl_down(lsum, off, 64);
        psum += __shfl_down(psum, off, 64);
        nsum += __shfl_down(nsum, off, 64);
    }
    if ((t & 63) == 0) {
        red[0][t >> 6] = lsum; red[1][t >> 6] = psum; red[2][t >> 6] = nsum;
    }
    __syncthreads();
    if (t == 0) {
        lsum = 0.f; psum = 0.f; nsum = 0.f;
        #pragma unroll
        for (int w = 0; w < 16; ++w) {
            lsum += red[0][w]; psum += red[1][w]; nsum += red[2][w];
        }
        out[0] = lsum / (float)NI;
        out[1] = psum / (float)NI;
        out[2] = nsum / ((float)NI * (float)(NI - 2));
    }
}

// ---------------------------------------------------------------------------
extern "C" void kernel_launch(void* const* d_in, const int* in_sizes, int n_in,
                              void* d_out, int out_size, void* d_ws, size_t ws_size,
                              hipStream_t stream) {
    const float* x1 = (const float*)d_in[0];
    const float* x2 = (const float*)d_in[1];
    float* out = (float*)d_out;

    char* ws = (char*)d_ws;
    __hip_bfloat16* Xb = (__hip_bfloat16*)ws;                 // NI*DIM*2 = 8 MB
    float* rnorm  = (float*)(ws + (size_t)NI * DIM * 2);      // NI
    float* posdot = rnorm + NI;                               // NS
    float* rowsum = posdot + NS;                              // NI (zeroed in prep)
    float* negpart = rowsum + NI;                             // NTRI (all written)

    prep_kernel<<<NS / 2, 256, 0, stream>>>(x1, x2, Xb, rnorm, posdot, rowsum);

    sim_kernel<<<NTRI, 512, 0, stream>>>(Xb, rnorm, rowsum, negpart);

    final_kernel<<<1, 1024, 0, stream>>>(rowsum, rnorm, posdot, negpart, out);
}

// Round 5
// 149.858 us; speedup vs baseline: 1.4717x; 1.0007x over previous
//
#include <hip/hip_runtime.h>
#include <hip/hip_bf16.h>
#include <math.h>

#define NS 4096          // samples per view
#define NI 8192          // total instances (2 views)
#define DIM 512
#define TEMP_INV 2.0f    // 1/t, t = 0.5
#define TILE 256         // output tile side
#define NBLK 32          // NI/TILE tile blocks per side
#define NTRI (NBLK * (NBLK + 1) / 2)   // 528 upper-triangle tiles
#define BK 64            // k-elems staged per step
#define NSTG (DIM / BK)  // 8 stages

typedef short v8s __attribute__((ext_vector_type(8)));   // 8 bf16 (4 VGPRs)
typedef float v4f __attribute__((ext_vector_type(4)));   // 4 fp32 acc

// async global->LDS, 16B per lane. LDS dest is wave-uniform base + lane*16.
__device__ __forceinline__ void gld16(const void* g, void* l) {
    __builtin_amdgcn_global_load_lds(
        (const __attribute__((address_space(1))) void*)g,
        (__attribute__((address_space(3))) void*)l, 16, 0, 0);
}

// ---------------------------------------------------------------------------
// Kernel 1: norms + positive dots (fp32), cast X -> bf16; also zeros rowsum.
// ---------------------------------------------------------------------------
__global__ __launch_bounds__(256) void prep_kernel(
        const float* __restrict__ x1, const float* __restrict__ x2,
        __hip_bfloat16* __restrict__ Xb, float* __restrict__ rnorm,
        float* __restrict__ posdot, float* __restrict__ rowsum) {
    const int t = threadIdx.x;
    if (t < 4) rowsum[blockIdx.x * 4 + t] = 0.f;   // 2048 blocks x 4 = NI
    const int sub = t >> 7;
    const int c4 = t & 127;
    const int i = blockIdx.x * 2 + sub;
    const float4 a = ((const float4*)(x1 + (size_t)i * DIM))[c4];
    const float4 b = ((const float4*)(x2 + (size_t)i * DIM))[c4];
    float s1 = a.x*a.x + a.y*a.y + a.z*a.z + a.w*a.w;
    float s2 = b.x*b.x + b.y*b.y + b.z*b.z + b.w*b.w;
    float dd = a.x*b.x + a.y*b.y + a.z*b.z + a.w*b.w;

    auto bfbits = [](float v) -> unsigned short {
        __hip_bfloat16 h = __float2bfloat16(v);
        return *(unsigned short*)&h;
    };
    ushort4 pa = { bfbits(a.x), bfbits(a.y), bfbits(a.z), bfbits(a.w) };
    ushort4 pb = { bfbits(b.x), bfbits(b.y), bfbits(b.z), bfbits(b.w) };
    ((ushort4*)(Xb + (size_t)i * DIM))[c4] = pa;
    ((ushort4*)(Xb + (size_t)(i + NS) * DIM))[c4] = pb;

    #pragma unroll
    for (int off = 32; off; off >>= 1) {
        s1 += __shfl_down(s1, off, 64);
        s2 += __shfl_down(s2, off, 64);
        dd += __shfl_down(dd, off, 64);
    }
    __shared__ float red[2][2][3];
    if ((t & 63) == 0) {
        const int w = (t >> 6) & 1;
        red[sub][w][0] = s1; red[sub][w][1] = s2; red[sub][w][2] = dd;
    }
    __syncthreads();
    if ((t & 127) == 0) {
        s1 = red[sub][0][0] + red[sub][1][0];
        s2 = red[sub][0][1] + red[sub][1][1];
        dd = red[sub][0][2] + red[sub][1][2];
        rnorm[i]      = 1.0f / sqrtf(s1);
        rnorm[i + NS] = 1.0f / sqrtf(s2);
        posdot[i] = dd;
    }
}

// ---------------------------------------------------------------------------
// Kernel 2: upper-triangle 256x256 tiles of G = Xb*Xb^T.
// 512 threads / 8 waves (2x4 grid); wave tile 128x64 -> acc[8][4] = 128 regs.
// 8-wave block => 2 waves/SIMD => 256-reg/wave budget (arch+acc unified).
// Rounds 1-3 spilled because address ARRAYS (~40 arch regs) + frag arrays
// (48) pushed arch past the 128 left after acc. This version collapses all
// addressing to compile-time immediates:
//   staging: lin=q*512+t => row=q*64+(t>>3), kc=(t&7)^((t>>3)&7)  (q-indep;
//            q adds 65536B global / 8192B LDS, both immediates)
//   frags:   slot = quad^(r16&7) (tt-indep; tt adds 2048B immediate,
//            s2 is ^64, B tile is +32768 immediate)
// and streams A-frags one at a time (live frags: bf[4]+a = 20 regs).
// Arch demand ~60 + acc 128 ~= 190 < 256 -> no scratch (tripwire:
// WRITE_SIZE must drop 18.4 MB -> ~1.5 MB).
// Same numerics as round 3 (passed, absmax 3e-8); only materialization
// changed. Sync: barrier (drains prev prefetch) -> prefetch other buf ->
// compute; swizzle slot cs = kc^(row&7): 0 conflicts measured.
// ---------------------------------------------------------------------------
__global__ __launch_bounds__(512, 2) void sim_kernel(
        const __hip_bfloat16* __restrict__ Xbh, const float* __restrict__ rnorm,
        float* __restrict__ rowsum, float* __restrict__ negpart) {
    // --- XCD-aware bijective swizzle: 528 = 8 * 66 exactly
    const int raw = blockIdx.x;
    const int id = (raw & 7) * 66 + (raw >> 3);
    // --- triangular decode: id -> (bi, bj), bi<=bj, NBLK=32
    int bi = (int)((65.0f - sqrtf(4225.0f - 8.0f * (float)id)) * 0.5f);
    int base = bi * (65 - bi) / 2;
    if (id < base)                       { --bi; base = bi * (65 - bi) / 2; }
    else if (id >= base + (NBLK - bi))   { ++bi; base = bi * (65 - bi) / 2; }
    const int bj = bi + (id - base);
    const bool offdiag = (bj != bi);
    const int i0 = bi * TILE, j0 = bj * TILE;

    __shared__ __align__(16) short lds[2][2][TILE * BK];   // [buf][A/B], 128 KB
    __shared__ float sRow[4][TILE];            // [wc][row]   4 KB
    __shared__ float sCol[2][TILE];            // [wr][col]   2 KB
    __shared__ float sNeg[8];

    const int t = threadIdx.x;                 // 0..511
    const int lane = t & 63, wv = t >> 6;      // 8 waves
    const int wr = wv >> 2, wc = wv & 3;       // 2 x 4 wave grid
    const int r16 = lane & 15, quad = lane >> 4;

    const short* X = reinterpret_cast<const short*>(Xbh);

    // --- staging bases (q-independent; q strides are immediates)
    const int grow = t >> 3;                           // 0..63
    const int kc   = (t & 7) ^ (grow & 7);
    const int gA   = (i0 + grow) * DIM + kc * 8;       // short index
    const int gB   = (j0 + grow) * DIM + kc * 8;
    const int lbs  = wv * 512;                         // short index in tile

    // --- fragment read bases (bytes within a 32 KB tile; tt adds 2048)
    const int slot = (quad ^ (r16 & 7)) * 16;
    const int aoff = (wr * 128 + r16) * 128 + slot;
    const int boff = (wc * 64  + r16) * 128 + slot;

    v4f acc[8][4];
    #pragma unroll
    for (int a = 0; a < 8; ++a)
        #pragma unroll
        for (int b = 0; b < 4; ++b)
            acc[a][b] = (v4f){0.f, 0.f, 0.f, 0.f};

    // --- prologue: stage first chunk into buf0
    #pragma unroll
    for (int q = 0; q < 4; ++q) {
        gld16(X + gA + q * 32768, &lds[0][0][lbs + q * 4096]);
        gld16(X + gB + q * 32768, &lds[0][1][lbs + q * 4096]);
    }

    const char* ldsb = (const char*)&lds[0][0][0];

    // --- main loop: 8 stages of BK=64
    for (int s = 0; s < NSTG; ++s) {
        const int cur = s & 1;
        __syncthreads();                       // buf[cur] complete (vmcnt drain)
        if (s + 1 < NSTG) {                    // prefetch next, in flight during compute
            const int k0 = (s + 1) * BK;
            #pragma unroll
            for (int q = 0; q < 4; ++q) {
                gld16(X + gA + k0 + q * 32768, &lds[1 - cur][0][lbs + q * 4096]);
                gld16(X + gB + k0 + q * 32768, &lds[1 - cur][1][lbs + q * 4096]);
            }
        }
        const char* tA = ldsb + cur * 65536;   // A tile base (B = +32768)
        #pragma unroll
        for (int s2 = 0; s2 < 2; ++s2) {
            const int ax = aoff ^ (s2 << 6);
            const int bx = boff ^ (s2 << 6);
            v8s bf[4];
            #pragma unroll
            for (int tb = 0; tb < 4; ++tb)
                bf[tb] = *(const v8s*)(tA + 32768 + bx + tb * 2048);
            __builtin_amdgcn_s_setprio(1);
            #pragma unroll
            for (int ta = 0; ta < 8; ++ta) {
                const v8s a = *(const v8s*)(tA + ax + ta * 2048);
                #pragma unroll
                for (int tb = 0; tb < 4; ++tb)
                    acc[ta][tb] = __builtin_amdgcn_mfma_f32_16x16x32_bf16(
                        a, bf[tb], acc[ta][tb], 0, 0, 0);
            }
            __builtin_amdgcn_s_setprio(0);
        }
    }

    // --- epilogue: sim2 = 2*D*r_i*r_j; masked (j==i, j==i^NS) -> exp contributes 1
    float rc[4];
    int colg[4];
    #pragma unroll
    for (int tb = 0; tb < 4; ++tb) {
        colg[tb] = j0 + wc * 64 + tb * 16 + r16;
        rc[tb] = rnorm[colg[tb]];
    }
    float negacc = 0.f;
    float colacc[4] = {0.f, 0.f, 0.f, 0.f};
    #pragma unroll
    for (int ta = 0; ta < 8; ++ta) {
        #pragma unroll
        for (int r = 0; r < 4; ++r) {
            const int rowl = wr * 128 + ta * 16 + quad * 4 + r;
            const int rowg = i0 + rowl;
            const float rr = rnorm[rowg] * TEMP_INV;
            float rowe = 0.f;
            #pragma unroll
            for (int tb = 0; tb < 4; ++tb) {
                const float sim2 = acc[ta][tb][r] * rr * rc[tb];
                const bool masked = (colg[tb] == rowg) || (colg[tb] == (rowg ^ NS));
                const float e = masked ? 1.0f : __expf(sim2);
                rowe   += e;
                negacc += masked ? 0.0f : sim2;
                colacc[tb] += e;
            }
            #pragma unroll
            for (int off = 1; off < 16; off <<= 1)
                rowe += __shfl_xor(rowe, off, 64);
            if (r16 == 0) sRow[wc][rowl] = rowe;
        }
    }
    #pragma unroll
    for (int tb = 0; tb < 4; ++tb) {
        colacc[tb] += __shfl_xor(colacc[tb], 16, 64);
        colacc[tb] += __shfl_xor(colacc[tb], 32, 64);
        if (quad == 0) sCol[wr][wc * 64 + tb * 16 + r16] = colacc[tb];
    }
    if (offdiag) negacc *= 2.0f;
    #pragma unroll
    for (int off = 1; off < 64; off <<= 1)
        negacc += __shfl_xor(negacc, off, 64);
    if (lane == 0) sNeg[wv] = negacc;

    __syncthreads();

    if (t < TILE) {
        atomicAdd(&rowsum[i0 + t],
                  sRow[0][t] + sRow[1][t] + sRow[2][t] + sRow[3][t]);
    } else if (offdiag) {
        const int c = t - TILE;
        atomicAdd(&rowsum[j0 + c], sCol[0][c] + sCol[1][c]);
    }
    if (t == 0) {
        float n = 0.f;
        #pragma unroll
        for (int w = 0; w < 8; ++w) n += sNeg[w];
        negpart[id] = n;
    }
}

// ---------------------------------------------------------------------------
// Kernel 3: final scalars. E_i = rowsum[i] (includes +2 from masked entries).
// ---------------------------------------------------------------------------
__global__ __launch_bounds__(1024) void final_kernel(
        const float* __restrict__ rowsum, const float* __restrict__ rnorm,
        const float* __restrict__ posdot, const float* __restrict__ negpart,
        float* __restrict__ out) {
    const int t = threadIdx.x;
    float lsum = 0.f, psum = 0.f, nsum = 0.f;
    #pragma unroll
    for (int i = t; i < NI; i += 1024) {
        const int s = i & (NS - 1);
        const float sp = posdot[s] * rnorm[i] * rnorm[i ^ NS] * TEMP_INV;
        const float E = rowsum[i];
        lsum += logf(expf(sp) + E) - sp;
        psum += sp;
    }
    if (t < NTRI)
        nsum = negpart[t];
    __shared__ float red[3][16];
    #pragma unroll
    for (int off = 32; off; off >>= 1) {
        lsum += __shfl_down(lsum, off, 64);
        psum += __shfl_down(psum, off, 64);
        nsum += __shfl_down(nsum, off, 64);
    }
    if ((t & 63) == 0) {
        red[0][t >> 6] = lsum; red[1][t >> 6] = psum; red[2][t >> 6] = nsum;
    }
    __syncthreads();
    if (t == 0) {
        lsum = 0.f; psum = 0.f; nsum = 0.f;
        #pragma unroll
        for (int w = 0; w < 16; ++w) {
            lsum += red[0][w]; psum += red[1][w]; nsum += red[2][w];
        }
        out[0] = lsum / (float)NI;
        out[1] = psum / (float)NI;
        out[2] = nsum / ((float)NI * (float)(NI - 2));
    }
}

// ---------------------------------------------------------------------------
extern "C" void kernel_launch(void* const* d_in, const int* in_sizes, int n_in,
                              void* d_out, int out_size, void* d_ws, size_t ws_size,
                              hipStream_t stream) {
    const float* x1 = (const float*)d_in[0];
    const float* x2 = (const float*)d_in[1];
    float* out = (float*)d_out;

    char* ws = (char*)d_ws;
    __hip_bfloat16* Xb = (__hip_bfloat16*)ws;                 // NI*DIM*2 = 8 MB
    float* rnorm  = (float*)(ws + (size_t)NI * DIM * 2);      // NI
    float* posdot = rnorm + NI;                               // NS
    float* rowsum = posdot + NS;                              // NI (zeroed in prep)
    float* negpart = rowsum + NI;                             // NTRI (all written)

    prep_kernel<<<NS / 2, 256, 0, stream>>>(x1, x2, Xb, rnorm, posdot, rowsum);

    sim_kernel<<<NTRI, 512, 0, stream>>>(Xb, rnorm, rowsum, negpart);

    final_kernel<<<1, 1024, 0, stream>>>(rowsum, rnorm, posdot, negpart, out);
}